// Round 6
// baseline (240.253 us; speedup 1.0000x reference)
//
#include <hip/hip_runtime.h>
#include <hip/hip_bf16.h>
#include <math.h>

#define N_NODES 50000
#define N_EDGES 800000
#define HDIM 64

#define NBUCKET 98        // buckets of 512 nodes: 98*512 = 50176 >= 50000
#define BSHIFT  9
#define BCAP    10240     // mean 8163, sd ~90 -> 23 sigma headroom

typedef short bf16x8 __attribute__((ext_vector_type(8)));
typedef float f32x4  __attribute__((ext_vector_type(4)));
typedef unsigned short ushort_t;

__device__ __forceinline__ ushort_t f2bf(float f) {
    __hip_bfloat16 b = __float2bfloat16(f);
    return *(ushort_t*)&b;
}
__device__ __forceinline__ void unpack4(uint2 u, float* f) {
    f[0] = __uint_as_float(u.x << 16); f[1] = __uint_as_float(u.x & 0xFFFF0000u);
    f[2] = __uint_as_float(u.y << 16); f[3] = __uint_as_float(u.y & 0xFFFF0000u);
}

// ---------------------------------------------------------------------------
// Prep: [0,3125) features->bf16; [3125,3221) W transpose+convert;
// block 3221: zero bucketFill + scalar + done counter.
// ---------------------------------------------------------------------------
__global__ __launch_bounds__(256) void prep_kernel(
    const float* __restrict__ features, ushort_t* __restrict__ x_bf,
    const float* __restrict__ V, const float* __restrict__ lw,
    ushort_t* __restrict__ Wt, int* __restrict__ bucketFill,
    float* __restrict__ scalar, unsigned int* __restrict__ done)
{
    const int b = blockIdx.x;
    const int t = threadIdx.x;
    if (b < 3125) {
        const int i = b * 256 + t;                   // < 800000 float4s
        const float4 v = ((const float4*)features)[i];
        ushort4 o = { f2bf(v.x), f2bf(v.y), f2bf(v.z), f2bf(v.w) };
        *(ushort4*)&x_bf[(size_t)i * 4] = o;
    } else if (b < 3221) {
        const int e = (b - 3125) * 256 + t;          // < 24576
        const int l = e / 12288, r = e % 12288;
        const int n = r / 192, k = r % 192;
        const int sel = k >> 6, i = k & 63;
        const float val = (sel < 2) ? V[l * 8192 + sel * 4096 + i * 64 + n]
                                    : lw[l * 4096 + i * 64 + n];
        Wt[e] = f2bf(val);
    } else {
        if (t < NBUCKET) bucketFill[t] = 0;
        if (t == NBUCKET) { scalar[0] = 0.0f; done[0] = 0u; }
    }
}

// ---------------------------------------------------------------------------
// K1: bucket scatter (see round 5). payload: src(16)|etype(3)<<16|dstloc(9)<<19
// ---------------------------------------------------------------------------
__global__ __launch_bounds__(256) void bucket_scatter(
    const int* __restrict__ src, const int* __restrict__ dst,
    const int* __restrict__ etype, int* __restrict__ bucketFill,
    unsigned int* __restrict__ buf)
{
    __shared__ int cnt[NBUCKET];
    __shared__ int base[NBUCKET];
    const int t = threadIdx.x;
    if (t < NBUCKET) cnt[t] = 0;
    __syncthreads();

    int rank[8], bkt[8];
    unsigned pay[8];
    bool valid[8];
#pragma unroll
    for (int k = 0; k < 8; ++k) {
        const int e = blockIdx.x * 2048 + k * 256 + t;
        valid[k] = (e < N_EDGES);
        if (valid[k]) {
            const int d = dst[e];
            const int b = d >> BSHIFT;
            bkt[k] = b;
            pay[k] = (unsigned)src[e] | ((unsigned)etype[e] << 16)
                   | ((unsigned)(d & 511) << 19);
            rank[k] = atomicAdd(&cnt[b], 1);
        }
    }
    __syncthreads();
    if (t < NBUCKET) base[t] = atomicAdd(&bucketFill[t], cnt[t]);
    __syncthreads();
#pragma unroll
    for (int k = 0; k < 8; ++k) {
        if (valid[k]) {
            const int pos = base[bkt[k]] + rank[k];
            if (pos < BCAP) buf[bkt[k] * BCAP + pos] = pay[k];
        }
    }
}

// ---------------------------------------------------------------------------
// K2: per-bucket sort -> dst-sorted edges + row_ptr (see round 5).
// ---------------------------------------------------------------------------
__global__ __launch_bounds__(256) void bucket_sort(
    const unsigned int* __restrict__ buf, const int* __restrict__ bucketFill,
    unsigned int* __restrict__ edges, int* __restrict__ row_ptr)
{
    __shared__ int hist[512];
    __shared__ int lscan[512];
    __shared__ int cnt2[512];
    __shared__ int sfill[128];
    __shared__ int sbase;
    const int b = blockIdx.x;
    const int t = threadIdx.x;

    hist[t] = 0; hist[t + 256] = 0;
    cnt2[t] = 0; cnt2[t + 256] = 0;
    if (t < NBUCKET) sfill[t] = bucketFill[t];
    else if (t < 128) sfill[t] = 0;
    __syncthreads();

    for (int off = 1; off < 128; off <<= 1) {
        int u = (t >= off && t < 128) ? sfill[t - off] : 0;
        __syncthreads();
        if (t < 128) sfill[t] += u;
        __syncthreads();
    }
    const int cntb = min(bucketFill[b], BCAP);
    if (t == 0) sbase = sfill[b] - bucketFill[b];
    __syncthreads();
    const int bb = sbase;

    for (int i = t; i < cntb; i += 256)
        atomicAdd(&hist[buf[b * BCAP + i] >> 19], 1);
    __syncthreads();

    if (t < 64) {
        int carry = 0;
        for (int c = 0; c < 8; ++c) {
            const int h = hist[c * 64 + t];
            int x = h;
#pragma unroll
            for (int off = 1; off < 64; off <<= 1) {
                int u = __shfl_up(x, off, 64);
                if (t >= off) x += u;
            }
            lscan[c * 64 + t] = carry + x - h;
            carry += __shfl(x, 63, 64);
        }
    }
    __syncthreads();

    const int n0 = b << BSHIFT;
    for (int i = t; i < 512; i += 256) {
        const int g = n0 + i;
        if (g < N_NODES) row_ptr[g] = bb + lscan[i];
    }
    if (b == NBUCKET - 1 && t == 0) row_ptr[N_NODES] = bb + cntb;

    for (int i = t; i < cntb; i += 256) {
        const unsigned p = buf[b * BCAP + i];
        const int d = p >> 19;
        const int r = atomicAdd(&cnt2[d], 1);
        edges[bb + lscan[d] + r] = p & 0x7FFFFu;   // src | etype<<16
    }
}

// ---------------------------------------------------------------------------
// Fused layer: block = 64 nodes (4 waves x 16 rows).
// Phase 1: each wave aggregates its 16 rows directly into the LDS U-tile
//          (y0,y1 in cols [0,128)) and stages self rows x (cols [128,192)).
//          Aggregation: 4 edge slots (g=lane>>4) x 16 feature-pairs
//          (fh=lane&15, 8B loads), 2 chains -> 8 edges/iter (~23% pad waste).
// Phase 2: barrier, then MFMA U[64x192] @ W[192x64] with W in registers.
//  !FUSE: writes relu(h) bf16 -> xout.   FUSE: h . fc_w -> scalar; the
//  last-finishing block applies sigmoid and writes out (device-scope atomics).
// ---------------------------------------------------------------------------
template <bool FUSE>
__global__ __launch_bounds__(256) void layer_fused(
    const ushort_t* __restrict__ x,      // [N,64] bf16 (gather + self)
    const unsigned int* __restrict__ edges,
    const int* __restrict__ row_ptr,
    const float* __restrict__ comp_l,    // [8,2] f32 this layer
    const ushort_t* __restrict__ Wt,     // [64,192] this layer
    const float* __restrict__ bias,      // [64]
    const float* __restrict__ fcw,       // [N*64] (FUSE)
    ushort_t* __restrict__ xout,         // [N,64] (!FUSE)
    float* __restrict__ scalar,          // [1]    (FUSE)
    unsigned int* __restrict__ done,     // [1]    (FUSE)
    const float* __restrict__ fcb,       // [1]    (FUSE)
    float* __restrict__ out)             // [1]    (FUSE)
{
    __shared__ __align__(16) ushort_t su[64 * 200];   // 200 = 192 + 8 pad
    __shared__ float sred[4];
    const int t = threadIdx.x;
    const int w = t >> 6;
    const int lane = t & 63;
    const int tile = blockIdx.x;

    // --- W fragments + bias, once per wave ---
    const int c16 = lane & 15;
    const int quad = lane >> 4;
    bf16x8 wf[6];
#pragma unroll
    for (int kf = 0; kf < 6; ++kf)
        wf[kf] = *(const bf16x8*)&Wt[(w * 16 + c16) * 192 + kf * 32 + quad * 8];
    const float bv = bias[w * 16 + c16];

    // --- stage self rows x into cols [128,192) of this wave's 16 rows ---
#pragma unroll
    for (int p = 0; p < 2; ++p) {
        const int row = w * 16 + p * 8 + (lane >> 3);
        const int n = tile * 64 + row;
        uint4 v = {0u, 0u, 0u, 0u};
        if (n < N_NODES) v = *(const uint4*)&x[(size_t)n * 64 + (lane & 7) * 8];
        *(uint4*)&su[row * 200 + 128 + (lane & 7) * 8] = v;
    }

    // --- aggregate this wave's 16 rows into cols [0,128) ---
    const int g  = lane >> 4;     // edge slot 0..3
    const int fh = lane & 15;     // feature group of 4
    for (int r = 0; r < 16; ++r) {
        const int row = w * 16 + r;
        const int n = tile * 64 + row;
        int beg = 0, end = 0;
        if (n < N_NODES) { beg = row_ptr[n]; end = row_ptr[n + 1]; }
        float a0[4] = {0.f, 0.f, 0.f, 0.f};
        float a1[4] = {0.f, 0.f, 0.f, 0.f};
        for (int j = beg; j < end; j += 8) {
            const int j0 = j + g;
            const int j1 = j + 4 + g;
            const unsigned pk0 = edges[(j0 < end) ? j0 : (end - 1)];
            const unsigned pk1 = edges[(j1 < end) ? j1 : (end - 1)];
            float2 c0 = *(const float2*)&comp_l[((pk0 >> 16) & 7) * 2];
            float2 c1 = *(const float2*)&comp_l[((pk1 >> 16) & 7) * 2];
            if (j0 >= end) { c0.x = 0.f; c0.y = 0.f; }
            if (j1 >= end) { c1.x = 0.f; c1.y = 0.f; }
            const uint2 u0 = *(const uint2*)&x[(size_t)(pk0 & 0xFFFFu) * 64 + fh * 4];
            const uint2 u1 = *(const uint2*)&x[(size_t)(pk1 & 0xFFFFu) * 64 + fh * 4];
            float f0[4], f1[4];
            unpack4(u0, f0);
            unpack4(u1, f1);
#pragma unroll
            for (int i = 0; i < 4; ++i) {
                a0[i] = fmaf(c0.x, f0[i], a0[i]); a1[i] = fmaf(c0.y, f0[i], a1[i]);
                a0[i] = fmaf(c1.x, f1[i], a0[i]); a1[i] = fmaf(c1.y, f1[i], a1[i]);
            }
        }
        // fold 4 edge slots (lane bits 4,5)
#pragma unroll
        for (int m = 16; m <= 32; m <<= 1) {
#pragma unroll
            for (int i = 0; i < 4; ++i) {
                a0[i] += __shfl_xor(a0[i], m, 64);
                a1[i] += __shfl_xor(a1[i], m, 64);
            }
        }
        if (g == 0) {
            ushort4 o0 = { f2bf(a0[0]), f2bf(a0[1]), f2bf(a0[2]), f2bf(a0[3]) };
            ushort4 o1 = { f2bf(a1[0]), f2bf(a1[1]), f2bf(a1[2]), f2bf(a1[3]) };
            *(ushort4*)&su[row * 200 + fh * 4]      = o0;
            *(ushort4*)&su[row * 200 + 64 + fh * 4] = o1;
        }
    }
    __syncthreads();

    // --- phase 2: MFMA  h = U @ W + bias ---
    float fsum = 0.f;
#pragma unroll
    for (int mt = 0; mt < 4; ++mt) {
        f32x4 acc = {bv, bv, bv, bv};
#pragma unroll
        for (int kf = 0; kf < 6; ++kf) {
            const bf16x8 af =
                *(const bf16x8*)&su[(mt * 16 + c16) * 200 + kf * 32 + quad * 8];
            acc = __builtin_amdgcn_mfma_f32_16x16x32_bf16(af, wf[kf], acc, 0, 0, 0);
        }
        const int nodeb = tile * 64 + mt * 16 + quad * 4;
        if (FUSE) {
#pragma unroll
            for (int r = 0; r < 4; ++r) {
                const int n = nodeb + r;
                if (n < N_NODES)
                    fsum += acc[r] * fcw[(size_t)n * 64 + w * 16 + c16];
            }
        } else {
#pragma unroll
            for (int r = 0; r < 4; ++r) {
                const int n = nodeb + r;
                if (n < N_NODES)
                    xout[(size_t)n * 64 + w * 16 + c16] = f2bf(fmaxf(acc[r], 0.f));
            }
        }
    }

    if (FUSE) {
#pragma unroll
        for (int off = 32; off; off >>= 1) fsum += __shfl_down(fsum, off, 64);
        if (lane == 0) sred[w] = fsum;
        __syncthreads();
        if (t == 0) {
            atomicAdd(scalar, sred[0] + sred[1] + sred[2] + sred[3]);
            __threadfence();
            const unsigned old = atomicAdd(done, 1u);
            if (old == gridDim.x - 1) {
                const float v = atomicAdd(scalar, 0.0f) + fcb[0];
                out[0] = 1.0f / (1.0f + expf(-v));
            }
        }
    }
}

// ---------------------------------------------------------------------------
extern "C" void kernel_launch(void* const* d_in, const int* in_sizes, int n_in,
                              void* d_out, int out_size, void* d_ws, size_t ws_size,
                              hipStream_t stream)
{
    const float* features = (const float*)d_in[0];  // [50000, 64]
    const float* V        = (const float*)d_in[1];  // [2, 2, 64, 64]
    const float* comp     = (const float*)d_in[2];  // [2, 8, 2]
    const float* loop_w   = (const float*)d_in[3];  // [2, 64, 64]
    const float* bias     = (const float*)d_in[4];  // [2, 64]
    const float* fc_w     = (const float*)d_in[5];  // [1, 50000*64]
    const float* fc_b     = (const float*)d_in[6];  // [1]
    const int*   src      = (const int*)d_in[7];
    const int*   dst      = (const int*)d_in[8];
    const int*   etype    = (const int*)d_in[9];
    float* out = (float*)d_out;

    char* ws = (char*)d_ws;
    ushort_t*     x_bf    = (ushort_t*)(ws);                 //  6,400,000 B
    ushort_t*     x1_bf   = (ushort_t*)(ws + 6400000);       //  6,400,000 B
    ushort_t*     Wt      = (ushort_t*)(ws + 12800000);      //     49,152 B
    float*        scalar  = (float*)   (ws + 12849152);      //          4 B
    unsigned int* done    = (unsigned int*)(ws + 12849280);  //          4 B
    int*          bucketFill = (int*)  (ws + 12849408);      //        392 B
    int*          row_ptr = (int*)     (ws + 12849920);      //    200,004 B
    unsigned int* edges   = (unsigned int*)(ws + 13049984);  //  3,200,000 B
    unsigned int* buf     = (unsigned int*)(ws + 16249984);  //  4,014,080 B
                                                             // end ~20.3 MB

    const int k1Blocks = (N_EDGES + 2047) / 2048;   // 391
    const int lBlocks  = (N_NODES + 63) / 64;       // 782

    // ---- prep (bf16 converts + zero counters) + bucketed CSR build ----
    prep_kernel<<<3222, 256, 0, stream>>>(features, x_bf, V, loop_w, Wt,
                                          bucketFill, scalar, done);
    bucket_scatter<<<k1Blocks, 256, 0, stream>>>(src, dst, etype, bucketFill, buf);
    bucket_sort<<<NBUCKET, 256, 0, stream>>>(buf, bucketFill, edges, row_ptr);

    // ---- layer 0 (agg + transform fused) ----
    layer_fused<false><<<lBlocks, 256, 0, stream>>>(
        x_bf, edges, row_ptr, comp, Wt, bias,
        nullptr, x1_bf, nullptr, nullptr, nullptr, nullptr);

    // ---- layer 1 (agg + transform + fc dot + sigmoid fused) ----
    layer_fused<true><<<lBlocks, 256, 0, stream>>>(
        x1_bf, edges, row_ptr, comp + 16, Wt + 12288, bias + 64,
        fc_w, nullptr, scalar, done, fc_b, out);
}

// Round 7
// 207.772 us; speedup vs baseline: 1.1563x; 1.1563x over previous
//
#include <hip/hip_runtime.h>
#include <hip/hip_bf16.h>
#include <math.h>

#define N_NODES 50000
#define N_EDGES 800000
#define HDIM 64

#define NBUCKET 98        // buckets of 512 nodes: 98*512 = 50176 >= 50000
#define BSHIFT  9
#define BCAP    10240     // mean 8163, sd ~90 -> 23 sigma headroom

typedef short bf16x8 __attribute__((ext_vector_type(8)));
typedef float f32x4  __attribute__((ext_vector_type(4)));
typedef unsigned short ushort_t;

__device__ __forceinline__ ushort_t f2bf(float f) {
    __hip_bfloat16 b = __float2bfloat16(f);
    return *(ushort_t*)&b;
}
__device__ __forceinline__ void unpack8(uint4 u, float* f) {
    f[0] = __uint_as_float(u.x << 16); f[1] = __uint_as_float(u.x & 0xFFFF0000u);
    f[2] = __uint_as_float(u.y << 16); f[3] = __uint_as_float(u.y & 0xFFFF0000u);
    f[4] = __uint_as_float(u.z << 16); f[5] = __uint_as_float(u.z & 0xFFFF0000u);
    f[6] = __uint_as_float(u.w << 16); f[7] = __uint_as_float(u.w & 0xFFFF0000u);
}

// ---------------------------------------------------------------------------
// Fused prep+scatter: [0,3125) features->bf16; [3125,3221) W convert;
// [3221,3612) bucket scatter (counters pre-zeroed by a 512 B memset).
// Scatter payload: src(16) | etype(3)<<16 | dstloc(9)<<19.
// ---------------------------------------------------------------------------
__global__ __launch_bounds__(256) void prep_scatter(
    const float* __restrict__ features, ushort_t* __restrict__ x_bf,
    const float* __restrict__ V, const float* __restrict__ lw,
    ushort_t* __restrict__ Wt,
    const int* __restrict__ src, const int* __restrict__ dst,
    const int* __restrict__ etype, int* __restrict__ bucketFill,
    unsigned int* __restrict__ buf)
{
    __shared__ int cnt[NBUCKET];
    __shared__ int base[NBUCKET];
    const int b = blockIdx.x;
    const int t = threadIdx.x;
    if (b < 3125) {
        const int i = b * 256 + t;                   // < 800000 float4s
        const float4 v = ((const float4*)features)[i];
        ushort4 o = { f2bf(v.x), f2bf(v.y), f2bf(v.z), f2bf(v.w) };
        *(ushort4*)&x_bf[(size_t)i * 4] = o;
        return;
    }
    if (b < 3221) {
        const int e = (b - 3125) * 256 + t;          // < 24576
        const int l = e / 12288, r = e % 12288;
        const int n = r / 192, k = r % 192;
        const int sel = k >> 6, i = k & 63;
        const float val = (sel < 2) ? V[l * 8192 + sel * 4096 + i * 64 + n]
                                    : lw[l * 4096 + i * 64 + n];
        Wt[e] = f2bf(val);
        return;
    }
    // ---- bucket scatter ----
    const int blk = b - 3221;                        // 0..390
    if (t < NBUCKET) cnt[t] = 0;
    __syncthreads();

    int rank[8], bkt[8];
    unsigned pay[8];
    bool valid[8];
#pragma unroll
    for (int k = 0; k < 8; ++k) {
        const int e = blk * 2048 + k * 256 + t;
        valid[k] = (e < N_EDGES);
        if (valid[k]) {
            const int d = dst[e];
            const int bb = d >> BSHIFT;
            bkt[k] = bb;
            pay[k] = (unsigned)src[e] | ((unsigned)etype[e] << 16)
                   | ((unsigned)(d & 511) << 19);
            rank[k] = atomicAdd(&cnt[bb], 1);
        }
    }
    __syncthreads();
    if (t < NBUCKET) base[t] = atomicAdd(&bucketFill[t], cnt[t]);
    __syncthreads();
#pragma unroll
    for (int k = 0; k < 8; ++k) {
        if (valid[k]) {
            const int pos = base[bkt[k]] + rank[k];
            if (pos < BCAP) buf[bkt[k] * BCAP + pos] = pay[k];
        }
    }
}

// ---------------------------------------------------------------------------
// K2: per-bucket sort -> dst-sorted edges + row_ptr.
// ---------------------------------------------------------------------------
__global__ __launch_bounds__(256) void bucket_sort(
    const unsigned int* __restrict__ buf, const int* __restrict__ bucketFill,
    unsigned int* __restrict__ edges, int* __restrict__ row_ptr)
{
    __shared__ int hist[512];
    __shared__ int lscan[512];
    __shared__ int cnt2[512];
    __shared__ int sfill[128];
    __shared__ int sbase;
    const int b = blockIdx.x;
    const int t = threadIdx.x;

    hist[t] = 0; hist[t + 256] = 0;
    cnt2[t] = 0; cnt2[t + 256] = 0;
    if (t < NBUCKET) sfill[t] = bucketFill[t];
    else if (t < 128) sfill[t] = 0;
    __syncthreads();

    for (int off = 1; off < 128; off <<= 1) {
        int u = (t >= off && t < 128) ? sfill[t - off] : 0;
        __syncthreads();
        if (t < 128) sfill[t] += u;
        __syncthreads();
    }
    const int cntb = min(bucketFill[b], BCAP);
    if (t == 0) sbase = sfill[b] - bucketFill[b];
    __syncthreads();
    const int bb = sbase;

    for (int i = t; i < cntb; i += 256)
        atomicAdd(&hist[buf[b * BCAP + i] >> 19], 1);
    __syncthreads();

    if (t < 64) {
        int carry = 0;
        for (int c = 0; c < 8; ++c) {
            const int h = hist[c * 64 + t];
            int x = h;
#pragma unroll
            for (int off = 1; off < 64; off <<= 1) {
                int u = __shfl_up(x, off, 64);
                if (t >= off) x += u;
            }
            lscan[c * 64 + t] = carry + x - h;
            carry += __shfl(x, 63, 64);
        }
    }
    __syncthreads();

    const int n0 = b << BSHIFT;
    for (int i = t; i < 512; i += 256) {
        const int g = n0 + i;
        if (g < N_NODES) row_ptr[g] = bb + lscan[i];
    }
    if (b == NBUCKET - 1 && t == 0) row_ptr[N_NODES] = bb + cntb;

    for (int i = t; i < cntb; i += 256) {
        const unsigned p = buf[b * BCAP + i];
        const int d = p >> 19;
        const int r = atomicAdd(&cnt2[d], 1);
        edges[bb + lscan[d] + r] = p & 0x7FFFFu;   // src | etype<<16
    }
}

// ---------------------------------------------------------------------------
// Aggregate v3: 8 lanes per node (lane g_l owns 8 features = one uint4 row
// slice), 8 nodes per wave, 2 edges per round per group -> 16 gather-rows in
// flight per wave, ~5% pad waste, no cross-lane reduction. Edge words and
// comp are group-broadcast loads (L1-resident). f32 accumulate, bf16 out.
//   y[n,b,:] = sum_{e: dst=n} comp[etype_e][b] * x[src_e,:]
// ---------------------------------------------------------------------------
__global__ __launch_bounds__(256) void aggregate2(
    const ushort_t* __restrict__ x,      // [N,64] bf16
    const unsigned int* __restrict__ edges,
    const int* __restrict__ row_ptr,
    const float* __restrict__ comp_l,    // [8,2] f32 this layer
    ushort_t* __restrict__ y)            // [N,128] bf16
{
    const int lane = threadIdx.x & 63;
    const int wv   = threadIdx.x >> 6;
    const int grp  = lane >> 3;          // node group within wave
    const int gl   = lane & 7;           // feature octet within row
    const int n    = blockIdx.x * 32 + wv * 8 + grp;

    int beg = 0, end = 0;
    if (n < N_NODES) { beg = row_ptr[n]; end = row_ptr[n + 1]; }

    float a0[8], a1[8];
#pragma unroll
    for (int i = 0; i < 8; ++i) { a0[i] = 0.f; a1[i] = 0.f; }

    for (int j = beg; j < end; j += 2) {
        const unsigned pk0 = edges[j];
        const int j1 = j + 1;
        const unsigned pk1 = edges[(j1 < end) ? j1 : j];
        float2 c0 = *(const float2*)&comp_l[((pk0 >> 16) & 7) * 2];
        float2 c1 = *(const float2*)&comp_l[((pk1 >> 16) & 7) * 2];
        if (j1 >= end) { c1.x = 0.f; c1.y = 0.f; }
        const uint4 u0 = *(const uint4*)&x[(size_t)(pk0 & 0xFFFFu) * 64 + gl * 8];
        const uint4 u1 = *(const uint4*)&x[(size_t)(pk1 & 0xFFFFu) * 64 + gl * 8];
        float f0[8], f1[8];
        unpack8(u0, f0);
        unpack8(u1, f1);
#pragma unroll
        for (int i = 0; i < 8; ++i) {
            a0[i] = fmaf(c0.x, f0[i], a0[i]); a1[i] = fmaf(c0.y, f0[i], a1[i]);
            a0[i] = fmaf(c1.x, f1[i], a0[i]); a1[i] = fmaf(c1.y, f1[i], a1[i]);
        }
    }

    if (n < N_NODES) {
        uint4 o0, o1;
        o0.x = (unsigned)f2bf(a0[0]) | ((unsigned)f2bf(a0[1]) << 16);
        o0.y = (unsigned)f2bf(a0[2]) | ((unsigned)f2bf(a0[3]) << 16);
        o0.z = (unsigned)f2bf(a0[4]) | ((unsigned)f2bf(a0[5]) << 16);
        o0.w = (unsigned)f2bf(a0[6]) | ((unsigned)f2bf(a0[7]) << 16);
        o1.x = (unsigned)f2bf(a1[0]) | ((unsigned)f2bf(a1[1]) << 16);
        o1.y = (unsigned)f2bf(a1[2]) | ((unsigned)f2bf(a1[3]) << 16);
        o1.z = (unsigned)f2bf(a1[4]) | ((unsigned)f2bf(a1[5]) << 16);
        o1.w = (unsigned)f2bf(a1[6]) | ((unsigned)f2bf(a1[7]) << 16);
        *(uint4*)&y[(size_t)n * 128 + gl * 8]      = o0;
        *(uint4*)&y[(size_t)n * 128 + 64 + gl * 8] = o1;
    }
}

// ---------------------------------------------------------------------------
// MFMA node transform: h = U[64x192] @ W[192x64] + bias, U=[y0,y1,x] bf16,
// W in registers (6 frags/wave). Wave w owns output cols [16w,16w+16).
//  !FUSE: writes relu(h) bf16.  FUSE: h . fc_w -> scalar; last block applies
//  sigmoid and writes out (device-scope done counter).
// ---------------------------------------------------------------------------
template <bool FUSE>
__global__ __launch_bounds__(256) void mfma_transform(
    const ushort_t* __restrict__ y_bf,   // [N,128]
    const ushort_t* __restrict__ x_bf,   // [N,64]
    const ushort_t* __restrict__ Wt,     // [64,192] this layer (n-major)
    const float* __restrict__ bias,      // [64] f32
    const float* __restrict__ fcw,       // [N*64] (FUSE)
    ushort_t* __restrict__ xout,         // [N,64] (!FUSE)
    float* __restrict__ scalar,          // [1]    (FUSE)
    unsigned int* __restrict__ done,     // [1]    (FUSE)
    const float* __restrict__ fcb,       // [1]    (FUSE)
    float* __restrict__ out)             // [1]    (FUSE)
{
    __shared__ __align__(16) ushort_t su[64 * 200];   // 200 = 192 + 8 pad
    __shared__ float sred[4];
    const int t = threadIdx.x;
    const int w = t >> 6;
    const int lane = t & 63;
    const int c16 = lane & 15;
    const int quad = lane >> 4;
    const int tile = blockIdx.x;

    bf16x8 wf[6];
#pragma unroll
    for (int kf = 0; kf < 6; ++kf)
        wf[kf] = *(const bf16x8*)&Wt[(w * 16 + c16) * 192 + kf * 32 + quad * 8];
    const float bv = bias[w * 16 + c16];

#pragma unroll
    for (int k = 0; k < 6; ++k) {
        const int cid = t + 256 * k;          // 0..1535
        const int row = cid / 24;
        const int part = cid % 24;
        const int n = tile * 64 + row;
        uint4 v = {0u, 0u, 0u, 0u};
        if (n < N_NODES) {
            v = (part < 16) ? *(const uint4*)&y_bf[(size_t)n * 128 + part * 8]
                            : *(const uint4*)&x_bf[(size_t)n * 64 + (part - 16) * 8];
        }
        *(uint4*)&su[row * 200 + part * 8] = v;
    }
    __syncthreads();

    float fsum = 0.f;
#pragma unroll
    for (int mt = 0; mt < 4; ++mt) {
        f32x4 acc = {bv, bv, bv, bv};
#pragma unroll
        for (int kf = 0; kf < 6; ++kf) {
            const bf16x8 af =
                *(const bf16x8*)&su[(mt * 16 + c16) * 200 + kf * 32 + quad * 8];
            acc = __builtin_amdgcn_mfma_f32_16x16x32_bf16(af, wf[kf], acc, 0, 0, 0);
        }
        const int nodeb = tile * 64 + mt * 16 + quad * 4;
        if (FUSE) {
#pragma unroll
            for (int r = 0; r < 4; ++r) {
                const int n = nodeb + r;
                if (n < N_NODES)
                    fsum += acc[r] * fcw[(size_t)n * 64 + w * 16 + c16];
            }
        } else {
#pragma unroll
            for (int r = 0; r < 4; ++r) {
                const int n = nodeb + r;
                if (n < N_NODES)
                    xout[(size_t)n * 64 + w * 16 + c16] = f2bf(fmaxf(acc[r], 0.f));
            }
        }
    }

    if (FUSE) {
#pragma unroll
        for (int off = 32; off; off >>= 1) fsum += __shfl_down(fsum, off, 64);
        if (lane == 0) sred[w] = fsum;
        __syncthreads();
        if (t == 0) {
            atomicAdd(scalar, sred[0] + sred[1] + sred[2] + sred[3]);
            __threadfence();
            const unsigned old = atomicAdd(done, 1u);
            if (old == gridDim.x - 1) {
                const float v = atomicAdd(scalar, 0.0f) + fcb[0];
                out[0] = 1.0f / (1.0f + expf(-v));
            }
        }
    }
}

// ---------------------------------------------------------------------------
extern "C" void kernel_launch(void* const* d_in, const int* in_sizes, int n_in,
                              void* d_out, int out_size, void* d_ws, size_t ws_size,
                              hipStream_t stream)
{
    const float* features = (const float*)d_in[0];  // [50000, 64]
    const float* V        = (const float*)d_in[1];  // [2, 2, 64, 64]
    const float* comp     = (const float*)d_in[2];  // [2, 8, 2]
    const float* loop_w   = (const float*)d_in[3];  // [2, 64, 64]
    const float* bias     = (const float*)d_in[4];  // [2, 64]
    const float* fc_w     = (const float*)d_in[5];  // [1, 50000*64]
    const float* fc_b     = (const float*)d_in[6];  // [1]
    const int*   src      = (const int*)d_in[7];
    const int*   dst      = (const int*)d_in[8];
    const int*   etype    = (const int*)d_in[9];
    float* out = (float*)d_out;

    char* ws = (char*)d_ws;
    ushort_t*     y_bf    = (ushort_t*)(ws);                 // 12,800,000 B
    ushort_t*     x_bf    = (ushort_t*)(ws + 12800000);      //  6,400,000 B
    ushort_t*     x1_bf   = (ushort_t*)(ws + 19200000);      //  6,400,000 B
    ushort_t*     Wt      = (ushort_t*)(ws + 25600000);      //     49,152 B
    int*          bucketFill = (int*)  (ws + 25649152);      //        392 B
    float*        scalar  = (float*)   (ws + 25649552);      //          4 B
    unsigned int* done    = (unsigned int*)(ws + 25649556);  //          4 B
    int*          row_ptr = (int*)     (ws + 25649664);      //    200,004 B
    unsigned int* edges   = (unsigned int*)(ws + 25849856);  //  3,200,000 B
    unsigned int* buf     = (unsigned int*)(ws + 29049856);  //  4,014,080 B
                                                             // end ~33.1 MB

    // zero bucketFill + scalar + done in one tiny memset
    hipMemsetAsync(bucketFill, 0, 512, stream);

    const int aggBlocks = (N_NODES + 31) / 32;      // 1563
    const int mtBlocks  = (N_NODES + 63) / 64;      // 782

    // ---- fused prep+scatter, then per-bucket sort ----
    prep_scatter<<<3612, 256, 0, stream>>>(features, x_bf, V, loop_w, Wt,
                                           src, dst, etype, bucketFill, buf);
    bucket_sort<<<NBUCKET, 256, 0, stream>>>(buf, bucketFill, edges, row_ptr);

    // ---- layer 0 ----
    aggregate2<<<aggBlocks, 256, 0, stream>>>(x_bf, edges, row_ptr, comp, y_bf);
    mfma_transform<false><<<mtBlocks, 256, 0, stream>>>(
        y_bf, x_bf, Wt, bias, nullptr, x1_bf, nullptr, nullptr, nullptr, nullptr);

    // ---- layer 1 + fused FC dot + sigmoid ----
    aggregate2<<<aggBlocks, 256, 0, stream>>>(x1_bf, edges, row_ptr, comp + 16, y_bf);
    mfma_transform<true><<<mtBlocks, 256, 0, stream>>>(
        y_bf, x1_bf, Wt + 12288, bias + 64, fc_w, nullptr, scalar, done, fc_b, out);
}